// Round 1
// baseline (996.093 us; speedup 1.0000x reference)
//
#include <hip/hip_runtime.h>

#define B_    32
#define C_    512
#define HW_   1024
#define N_    32768
#define M_    2048
#define K_    8
#define TN    64          // rows per block
#define TM    256         // items per tile
#define KC    32          // c chunk
#define NCH   (C_ / KC)   // 16
#define NTILE (M_ / TM)   // 8
#define NEG_INF (-1e30f)

// ---------------- transpose mempool [M][C] -> mpT [C][M] ----------------
__global__ __launch_bounds__(256) void transpose_k(const float* __restrict__ in,
                                                   float* __restrict__ out) {
    __shared__ float tile[32][33];
    const int bm = blockIdx.x * 32;
    const int bc = blockIdx.y * 32;
    const int tx = threadIdx.x & 31;
    const int ty = threadIdx.x >> 5;   // 0..7
#pragma unroll
    for (int i = 0; i < 4; ++i) {
        int m = ty + i * 8;
        tile[m][tx] = in[(size_t)(bm + m) * C_ + bc + tx];
    }
    __syncthreads();
#pragma unroll
    for (int i = 0; i < 4; ++i) {
        int c = ty + i * 8;
        out[(size_t)(bc + c) * M_ + bm + tx] = tile[tx][c];
    }
}

// ---------------- fused: GEMM + top-8 + softmax + combine ----------------
__global__ __launch_bounds__(256, 2) void memk(const float* __restrict__ x,
                                               const float* __restrict__ mempool,
                                               const float* __restrict__ mpT,
                                               float* __restrict__ out) {
    // arena unions: {q_lds[KC][TN] + mp_lds[KC][TM]} | att[TN][260] | cand
    __shared__ __align__(16) char arena[66560];
    __shared__ float w_lds[TN][K_];
    __shared__ int   i_lds[TN][K_];
    float* q_lds  = (float*)arena;                  // [KC][TN]   8 KiB
    float* mp_lds = (float*)(arena + KC * TN * 4);  // [KC][TM]  32 KiB
    float* att    = (float*)arena;                  // [TN][260] 65 KiB
    float* candv  = (float*)arena;                  // [TN][33]
    int*   candi  = (int*)(arena + TN * 33 * 4);    // [TN][33]

    const int t      = threadIdx.x;
    const int lane   = t & 63;
    const int wv     = t >> 6;       // wave id 0..3
    const int item_t = t & 31;
    const int row_t  = t >> 5;       // 0..7
    const int n0     = blockIdx.x * TN;
    const int b      = n0 >> 10;
    const int hw0    = n0 & 1023;
    const float* xb  = x + (size_t)b * C_ * HW_ + hw0;

    // scan mapping: 4 threads per row
    const int srow = t >> 2;
    const int stq  = t & 3;

    // running per-thread top-8 (ascending: sv[0] = min)
    float sv[K_];
    int   si[K_];
#pragma unroll
    for (int p = 0; p < K_; ++p) { sv[p] = NEG_INF; si[p] = 0x7fffffff; }

    for (int tile = 0; tile < NTILE; ++tile) {
        const int m0 = tile * TM;
        float acc[2][2][4][4];
#pragma unroll
        for (int rg = 0; rg < 2; ++rg)
#pragma unroll
            for (int ig = 0; ig < 2; ++ig)
#pragma unroll
                for (int i = 0; i < 4; ++i)
#pragma unroll
                    for (int j = 0; j < 4; ++j) acc[rg][ig][i][j] = 0.f;

        for (int ch = 0; ch < NCH; ++ch) {
            const int c0 = ch * KC;
            // stage q: q_lds[cl][hw] = x[b, c0+cl, hw0+hw]  (coalesced 256B/wave)
#pragma unroll
            for (int it = 0; it < 8; ++it) {
                int cl = wv + 4 * it;
                q_lds[cl * TN + lane] = xb[(size_t)(c0 + cl) * HW_ + lane];
            }
            // stage mp: mp_lds[cl][mm] = mpT[c0+cl][m0+mm]  (coalesced 1KiB/wave)
#pragma unroll
            for (int it = 0; it < 8; ++it) {
                int cl = wv + 4 * it;
                float4 v = *(const float4*)&mpT[(size_t)(c0 + cl) * M_ + m0 + lane * 4];
                *(float4*)&mp_lds[cl * TM + lane * 4] = v;
            }
            __syncthreads();
#pragma unroll 4
            for (int c = 0; c < KC; ++c) {
                float qv[8], mv[8];
                *(float4*)&qv[0] = *(const float4*)&q_lds[c * TN + row_t * 4];
                *(float4*)&qv[4] = *(const float4*)&q_lds[c * TN + 32 + row_t * 4];
                *(float4*)&mv[0] = *(const float4*)&mp_lds[c * TM + item_t * 4];
                *(float4*)&mv[4] = *(const float4*)&mp_lds[c * TM + 128 + item_t * 4];
#pragma unroll
                for (int rg = 0; rg < 2; ++rg)
#pragma unroll
                    for (int i = 0; i < 4; ++i)
#pragma unroll
                        for (int ig = 0; ig < 2; ++ig)
#pragma unroll
                            for (int j = 0; j < 4; ++j)
                                acc[rg][ig][i][j] =
                                    fmaf(qv[rg * 4 + i], mv[ig * 4 + j], acc[rg][ig][i][j]);
            }
            __syncthreads();
        }

        // dump att tile to LDS (overlaps staging arena; barriers serialize)
#pragma unroll
        for (int rg = 0; rg < 2; ++rg)
#pragma unroll
            for (int i = 0; i < 4; ++i) {
                int r = rg * 32 + row_t * 4 + i;
#pragma unroll
                for (int ig = 0; ig < 2; ++ig) {
                    float4 vv = make_float4(acc[rg][ig][i][0], acc[rg][ig][i][1],
                                            acc[rg][ig][i][2], acc[rg][ig][i][3]);
                    *(float4*)&att[r * 260 + ig * 128 + item_t * 4] = vv;
                }
            }
        __syncthreads();

        // scan: 4 threads per row, interleaved items (2-way-free bank pattern)
        for (int j = 0; j < 64; ++j) {
            int iloc = stq + 4 * j;
            float v = att[srow * 260 + iloc];
            if (v > sv[0]) {
                sv[0] = v;
                si[0] = m0 + iloc;
#pragma unroll
                for (int p = 0; p < K_ - 1; ++p) {
                    if (sv[p] > sv[p + 1]) {
                        float tv = sv[p]; sv[p] = sv[p + 1]; sv[p + 1] = tv;
                        int   ti = si[p]; si[p] = si[p + 1]; si[p + 1] = ti;
                    }
                }
            }
        }
        __syncthreads();   // protect att before next tile's staging
    }

    // write per-thread candidates
#pragma unroll
    for (int p = 0; p < K_; ++p) {
        candv[srow * 33 + stq * 8 + p] = sv[p];
        candi[srow * 33 + stq * 8 + p] = si[p];
    }
    __syncthreads();

    // leader per row: exact top-8 of 32 candidates + softmax
    if (t < TN) {
        const int row = t;
        float wv8[K_]; int wi8[K_];
#pragma unroll
        for (int sel = 0; sel < K_; ++sel) {
            float vb = NEG_INF; int ib = 0x7fffffff; int sb = 0;
            for (int s = 0; s < 32; ++s) {
                float v = candv[row * 33 + s];
                int  ii = candi[row * 33 + s];
                if (v > vb || (v == vb && ii < ib)) { vb = v; ib = ii; sb = s; }
            }
            candv[row * 33 + sb] = NEG_INF;
            wv8[sel] = vb; wi8[sel] = ib;
        }
        const float mx = wv8[0];
        float e[K_]; float sum = 0.f;
#pragma unroll
        for (int j = 0; j < K_; ++j) { e[j] = expf(wv8[j] - mx); sum += e[j]; }
        const float inv = 1.f / sum;
#pragma unroll
        for (int j = 0; j < K_; ++j) { w_lds[row][j] = e[j] * inv; i_lds[row][j] = wi8[j]; }
    }
    __syncthreads();

    // combine: out[b, c, hw0+crow] = sum_j w_j * mempool[idx_j][c]
    const int crow = t & 63;
    const int cw   = t >> 6;
    float wreg[K_]; int ireg[K_];
#pragma unroll
    for (int j = 0; j < K_; ++j) { wreg[j] = w_lds[crow][j]; ireg[j] = i_lds[crow][j]; }
    float* outb = out + (size_t)b * C_ * HW_ + hw0 + crow;
#pragma unroll 2
    for (int cg = 0; cg < 32; ++cg) {
        const int c = cw * 128 + cg * 4;
        float o0 = 0.f, o1 = 0.f, o2 = 0.f, o3 = 0.f;
#pragma unroll
        for (int j = 0; j < K_; ++j) {
            const float4 mp4 = *(const float4*)&mempool[(size_t)ireg[j] * C_ + c];
            o0 = fmaf(wreg[j], mp4.x, o0);
            o1 = fmaf(wreg[j], mp4.y, o1);
            o2 = fmaf(wreg[j], mp4.z, o2);
            o3 = fmaf(wreg[j], mp4.w, o3);
        }
        outb[(size_t)(c + 0) * HW_] = o0;
        outb[(size_t)(c + 1) * HW_] = o1;
        outb[(size_t)(c + 2) * HW_] = o2;
        outb[(size_t)(c + 3) * HW_] = o3;
    }
}

extern "C" void kernel_launch(void* const* d_in, const int* in_sizes, int n_in,
                              void* d_out, int out_size, void* d_ws, size_t ws_size,
                              hipStream_t stream) {
    const float* x       = (const float*)d_in[0];
    const float* mempool = (const float*)d_in[1];
    float* mpT = (float*)d_ws;                 // 512*2048*4 = 4 MiB
    float* o   = (float*)d_out;
    transpose_k<<<dim3(M_ / 32, C_ / 32), dim3(256), 0, stream>>>(mempool, mpT);
    memk<<<dim3(N_ / TN), dim3(256), 0, stream>>>(x, mempool, mpT, o);
}

// Round 2
// 866.015 us; speedup vs baseline: 1.1502x; 1.1502x over previous
//
#include <hip/hip_runtime.h>

typedef __attribute__((ext_vector_type(4))) float f32x4;
typedef __attribute__((ext_vector_type(8))) short short8;

#define B_    32
#define C_    512
#define HW_   1024
#define N_    32768
#define M_    2048
#define K_    8
#define TN    64
#define TM    256
#define NTILE 8
#define KSTEPS 16
#define NEG_INF (-1e30f)

// LDS arena layout (bytes)
#define AH_BASE    0
#define AH_STRIDE  1040            // 520 bf16 per row (512 + 8 pad)
#define AH_SIZE    (64 * 1040)     // 66560
#define BT_BASE    AH_SIZE
#define BT_ISTRIDE 80              // 40 bf16 per item (32 + 8 pad)
#define BT_SIZE    (256 * 80)      // 20480
#define ATT_BASE   (BT_BASE + BT_SIZE)   // 87040
#define ATT_STRIDE 260             // floats
#define ARENA_SIZE (ATT_BASE + 64 * ATT_STRIDE * 4)  // 153600
// overlays on ATT area (valid after all scans complete)
#define CV_OFF  0                  // candv [64][33] f32
#define CI_OFF  8448               // candi [64][33] int
#define SEL_OFF 16896              // selidx [64*16] int
#define RV_OFF  20992              // refv  [64*16] f32
#define WL_OFF  25088              // w_lds [64][8] f32
#define IL_OFF  27136              // i_lds [64][8] int

__device__ __forceinline__ unsigned short f2bf(float f) {
    unsigned u = __builtin_bit_cast(unsigned, f);
    u += 0x7fffu + ((u >> 16) & 1u);     // RNE
    return (unsigned short)(u >> 16);
}

// ---------------- mempool fp32 -> bf16 ----------------
__global__ __launch_bounds__(256) void convk(const float* __restrict__ in,
                                             unsigned short* __restrict__ ob) {
    int i = (blockIdx.x * 256 + threadIdx.x) * 4;
    float4 v = *(const float4*)(in + i);
    ushort4 o;
    o.x = f2bf(v.x); o.y = f2bf(v.y); o.z = f2bf(v.z); o.w = f2bf(v.w);
    *(ushort4*)(ob + i) = o;
}

// -------- fused: bf16-MFMA gating + top-k + fp32 refine + softmax + combine --------
__global__ __launch_bounds__(256, 1) void memk(const float* __restrict__ x,
                                               const float* __restrict__ mempool,
                                               const unsigned short* __restrict__ memb,
                                               float* __restrict__ out) {
    __shared__ __align__(16) char arena[ARENA_SIZE];
    unsigned short* AhU = (unsigned short*)(arena + AH_BASE);
    char* Bt    = arena + BT_BASE;
    float* att  = (float*)(arena + ATT_BASE);
    float* candv = (float*)(arena + ATT_BASE + CV_OFF);
    int*   candi = (int*)(arena + ATT_BASE + CI_OFF);
    int*   selidx = (int*)(arena + ATT_BASE + SEL_OFF);
    float* refv   = (float*)(arena + ATT_BASE + RV_OFF);
    float* w_lds  = (float*)(arena + ATT_BASE + WL_OFF);
    int*   i_lds  = (int*)(arena + ATT_BASE + IL_OFF);
    float* q_lds  = (float*)(arena + BT_BASE);   // refine phase overlay [64c][64r]

    const int t   = threadIdx.x;
    const int l   = t & 63;
    const int w   = t >> 6;        // wave 0..3 -> 64-item strip
    const int hi  = l >> 4;        // k-group
    const int l15 = l & 15;
    const int n0  = blockIdx.x * TN;
    const int b   = n0 >> 10;
    const int hw0 = n0 & 1023;

    // ---- stage A once: q bf16, row = l, c-quad = w (coalesced 256B x-reads) ----
    {
        const float* xp = x + (size_t)b * C_ * HW_ + hw0 + l;
        unsigned short* dst = AhU + l * 520;
#pragma unroll 8
        for (int j = 0; j < 128; ++j) {
            int c = w * 128 + j;
            dst[c] = f2bf(xp[(size_t)c * HW_]);
        }
    }

    // running per-thread top-8 over this thread's quarter (ascending)
    const int srow = t >> 2;
    const int stq  = t & 3;
    float sv[K_]; int si[K_];
#pragma unroll
    for (int p = 0; p < K_; ++p) { sv[p] = NEG_INF; si[p] = 0x7fffffff; }

    // prefetch B(tile0, ks0): item = t, 64B of bf16 k-chunk
    uint4 bpf0, bpf1, bpf2, bpf3;
    {
        const uint4* p = (const uint4*)(memb + (size_t)t * 512);
        bpf0 = p[0]; bpf1 = p[1]; bpf2 = p[2]; bpf3 = p[3];
    }

    for (int tile = 0; tile < NTILE; ++tile) {
        const int m0 = tile * TM;
        f32x4 acc[4][4];
#pragma unroll
        for (int rf = 0; rf < 4; ++rf)
#pragma unroll
            for (int itf = 0; itf < 4; ++itf) acc[rf][itf] = (f32x4)0.f;

        for (int ks = 0; ks < KSTEPS; ++ks) {
            __syncthreads();                       // prior reads of Bt done
            uint4* bw = (uint4*)(Bt + t * BT_ISTRIDE);
            bw[0] = bpf0; bw[1] = bpf1; bw[2] = bpf2; bw[3] = bpf3;
            __syncthreads();                       // Bt visible
            // issue next prefetch early (hides under MFMA)
            int nks = ks + 1, ntl = tile;
            if (nks == KSTEPS) { nks = 0; ++ntl; }
            if (ntl < NTILE) {
                const uint4* p = (const uint4*)(memb + (size_t)(ntl * TM + t) * 512 + nks * 32);
                bpf0 = p[0]; bpf1 = p[1]; bpf2 = p[2]; bpf3 = p[3];
            }
            short8 af[4], bf[4];
#pragma unroll
            for (int rf = 0; rf < 4; ++rf)
                af[rf] = *(const short8*)(arena + AH_BASE + (rf * 16 + l15) * AH_STRIDE + ks * 64 + hi * 16);
#pragma unroll
            for (int itf = 0; itf < 4; ++itf)
                bf[itf] = *(const short8*)(Bt + (w * 64 + itf * 16 + l15) * BT_ISTRIDE + hi * 16);
#pragma unroll
            for (int rf = 0; rf < 4; ++rf)
#pragma unroll
                for (int itf = 0; itf < 4; ++itf)
                    acc[rf][itf] = __builtin_amdgcn_mfma_f32_16x16x32_bf16(
                        af[rf], bf[itf], acc[rf][itf], 0, 0, 0);
        }

        // dump att tile: row = rf*16 + hi*4 + reg, item = w*64 + itf*16 + l15
#pragma unroll
        for (int rf = 0; rf < 4; ++rf)
#pragma unroll
            for (int itf = 0; itf < 4; ++itf) {
                int col = w * 64 + itf * 16 + l15;
#pragma unroll
                for (int reg = 0; reg < 4; ++reg)
                    att[(rf * 16 + hi * 4 + reg) * ATT_STRIDE + col] = acc[rf][itf][reg];
            }
        __syncthreads();

        // scan: 4 threads/row, interleaved quarters; maintain sorted top-8
        for (int j = 0; j < 64; ++j) {
            int iloc = stq + 4 * j;
            float v = att[srow * ATT_STRIDE + iloc];
            if (v > sv[0]) {
                sv[0] = v; si[0] = m0 + iloc;
#pragma unroll
                for (int p = 0; p < K_ - 1; ++p) {
                    if (sv[p] > sv[p + 1]) {
                        float tv = sv[p]; sv[p] = sv[p + 1]; sv[p + 1] = tv;
                        int   ti = si[p]; si[p] = si[p + 1]; si[p + 1] = ti;
                    }
                }
            }
        }
        __syncthreads();    // all scans done before att reuse / cand overlay
    }

    // write 32 candidates/row (overlay att area)
#pragma unroll
    for (int p = 0; p < K_; ++p) {
        candv[srow * 33 + stq * 8 + p] = sv[p];
        candi[srow * 33 + stq * 8 + p] = si[p];
    }
    __syncthreads();

    // leader: 4-way merge of sorted lists -> approx top-16 indices
    if (t < TN) {
        const int row = t;
        int pos[4] = {7, 7, 7, 7};
        for (int s = 0; s < 16; ++s) {
            float vb = NEG_INF; int ib = 0x7fffffff; int qb = 0;
#pragma unroll
            for (int q = 0; q < 4; ++q) {
                if (pos[q] >= 0) {
                    float v = candv[row * 33 + q * 8 + pos[q]];
                    int  ii = candi[row * 33 + q * 8 + pos[q]];
                    if (v > vb || (v == vb && ii < ib)) { vb = v; ib = ii; qb = q; }
                }
            }
            selidx[row * 16 + s] = ib;
            --pos[qb];
        }
    }
    __syncthreads();

    // exact fp32 refine: thread handles pairs p = t + 256*pp (row=p>>4, slot=p&15)
    int cnd[4];
#pragma unroll
    for (int pp = 0; pp < 4; ++pp) cnd[pp] = selidx[t + 256 * pp];
    float racc[4] = {0.f, 0.f, 0.f, 0.f};
    for (int ch = 0; ch < 8; ++ch) {
        const int c0 = ch * 64;
        __syncthreads();
#pragma unroll
        for (int i = 0; i < 16; ++i) {
            int idx = t + 256 * i;
            int c = idx >> 6, r = idx & 63;
            q_lds[c * 64 + r] = x[(size_t)b * C_ * HW_ + (size_t)(c0 + c) * HW_ + hw0 + r];
        }
        __syncthreads();
#pragma unroll
        for (int pp = 0; pp < 4; ++pp) {
            const int row = (t + 256 * pp) >> 4;
            const float4* mp = (const float4*)(mempool + (size_t)cnd[pp] * C_ + c0);
            float a = racc[pp];
#pragma unroll
            for (int c4 = 0; c4 < 16; ++c4) {
                float4 m4 = mp[c4];
                a = fmaf(q_lds[(c4 * 4 + 0) * 64 + row], m4.x, a);
                a = fmaf(q_lds[(c4 * 4 + 1) * 64 + row], m4.y, a);
                a = fmaf(q_lds[(c4 * 4 + 2) * 64 + row], m4.z, a);
                a = fmaf(q_lds[(c4 * 4 + 3) * 64 + row], m4.w, a);
            }
            racc[pp] = a;
        }
    }
#pragma unroll
    for (int pp = 0; pp < 4; ++pp) refv[t + 256 * pp] = racc[pp];
    __syncthreads();

    // leader: exact top-8 of 16 refined + softmax (fp32, index tie-break)
    if (t < TN) {
        const int row = t;
        float rv[16]; int ri[16];
#pragma unroll
        for (int s = 0; s < 16; ++s) { rv[s] = refv[row * 16 + s]; ri[s] = selidx[row * 16 + s]; }
        float wv8[K_]; int wi8[K_];
#pragma unroll
        for (int sel = 0; sel < K_; ++sel) {
            float vb = NEG_INF; int ib = 0x7fffffff; int sb = 0;
            for (int s = 0; s < 16; ++s) {
                if (rv[s] > vb || (rv[s] == vb && ri[s] < ib)) { vb = rv[s]; ib = ri[s]; sb = s; }
            }
            rv[sb] = NEG_INF;
            wv8[sel] = vb; wi8[sel] = ib;
        }
        const float mx = wv8[0];
        float e[K_]; float sum = 0.f;
#pragma unroll
        for (int j = 0; j < K_; ++j) { e[j] = expf(wv8[j] - mx); sum += e[j]; }
        const float inv = 1.f / sum;
#pragma unroll
        for (int j = 0; j < K_; ++j) { w_lds[row * 8 + j] = e[j] * inv; i_lds[row * 8 + j] = wi8[j]; }
    }
    __syncthreads();

    // combine: out[b, c, hw0+crow] = sum_j w_j * mempool[idx_j][c]
    const int crow = t & 63;
    const int cw   = t >> 6;
    float wreg[K_]; int ireg[K_];
#pragma unroll
    for (int j = 0; j < K_; ++j) { wreg[j] = w_lds[crow * 8 + j]; ireg[j] = i_lds[crow * 8 + j]; }
    float* outb = out + (size_t)b * C_ * HW_ + hw0 + crow;
#pragma unroll 2
    for (int cg = 0; cg < 32; ++cg) {
        const int c = cw * 128 + cg * 4;
        float o0 = 0.f, o1 = 0.f, o2 = 0.f, o3 = 0.f;
#pragma unroll
        for (int j = 0; j < K_; ++j) {
            const float4 mp4 = *(const float4*)&mempool[(size_t)ireg[j] * C_ + c];
            o0 = fmaf(wreg[j], mp4.x, o0);
            o1 = fmaf(wreg[j], mp4.y, o1);
            o2 = fmaf(wreg[j], mp4.z, o2);
            o3 = fmaf(wreg[j], mp4.w, o3);
        }
        outb[(size_t)(c + 0) * HW_] = o0;
        outb[(size_t)(c + 1) * HW_] = o1;
        outb[(size_t)(c + 2) * HW_] = o2;
        outb[(size_t)(c + 3) * HW_] = o3;
    }
}

extern "C" void kernel_launch(void* const* d_in, const int* in_sizes, int n_in,
                              void* d_out, int out_size, void* d_ws, size_t ws_size,
                              hipStream_t stream) {
    const float* x       = (const float*)d_in[0];
    const float* mempool = (const float*)d_in[1];
    unsigned short* memb = (unsigned short*)d_ws;    // 2048*512*2 = 2 MiB
    float* o = (float*)d_out;
    convk<<<dim3(M_ * C_ / (256 * 4)), dim3(256), 0, stream>>>(mempool, memb);
    memk<<<dim3(N_ / TN), dim3(256), 0, stream>>>(x, mempool, memb, o);
}

// Round 3
// 746.214 us; speedup vs baseline: 1.3349x; 1.1605x over previous
//
#include <hip/hip_runtime.h>

typedef __attribute__((ext_vector_type(4))) float f32x4;
typedef __attribute__((ext_vector_type(8))) short short8;

#define C_    512
#define HW_   1024
#define M_    2048
#define K_    8
#define TN    64
#define TM    256
#define NTILE 8
#define NKC   8            // 64-channel K-steps per tile
#define NEG_INF (-1e30f)

// ---- LDS arena (bytes) ----
#define AH_STRIDE 1056     // 528 bf16 per row; 66 x 16B units -> conflict-free frags
#define AH_SIZE   (64 * 1056)            // 67584
#define B0_BASE   AH_SIZE
#define BBUF      32768
#define B1_BASE   (B0_BASE + BBUF)
#define ATT_BASE  B0_BASE                // overlays B buffers (dead during scan)
#define ATT_STRIDE 260                   // floats
#define ARENA_SIZE (ATT_BASE + 64 * ATT_STRIDE * 4)   // 134144
// overlays inside ATT region (valid after all scans)
#define CV_OFF  0
#define CI_OFF  8448
#define SEL_OFF 16896
#define RV_OFF  20992
#define WL_OFF  25088
#define IL_OFF  27136

__device__ __forceinline__ unsigned short f2bf(float f) {
    unsigned u = __builtin_bit_cast(unsigned, f);
    u += 0x7fffu + ((u >> 16) & 1u);     // RNE
    return (unsigned short)(u >> 16);
}

// ---- repack mempool [M][C] fp32 -> membR [(c/64)*M + m][c%64] bf16 ----
__global__ __launch_bounds__(256) void convk(const float* __restrict__ in,
                                             unsigned short* __restrict__ ob) {
    int i = (blockIdx.x * 256 + threadIdx.x) * 4;
    int m = i >> 9, c = i & 511;
    float4 v = *(const float4*)(in + i);
    ushort4 o;
    o.x = f2bf(v.x); o.y = f2bf(v.y); o.z = f2bf(v.z); o.w = f2bf(v.w);
    int kc = c >> 6, cc = c & 63;
    *(ushort4*)(ob + (((size_t)(kc * M_ + m)) << 6) + cc) = o;
}

// -------- fused: bf16-MFMA gating + top-k + fp32 refine + softmax + combine --------
__global__ __launch_bounds__(256, 1) void memk(const float* __restrict__ x,
                                               const float* __restrict__ mempool,
                                               const unsigned short* __restrict__ membR,
                                               float* __restrict__ out) {
    __shared__ __align__(16) char arena[ARENA_SIZE];
    unsigned short* AhU = (unsigned short*)arena;
    float* att   = (float*)(arena + ATT_BASE);
    float* candv = (float*)(arena + ATT_BASE + CV_OFF);
    int*   candi = (int*)(arena + ATT_BASE + CI_OFF);
    int*   selidx = (int*)(arena + ATT_BASE + SEL_OFF);
    float* refv   = (float*)(arena + ATT_BASE + RV_OFF);
    float* w_lds  = (float*)(arena + ATT_BASE + WL_OFF);
    int*   i_lds  = (int*)(arena + ATT_BASE + IL_OFF);
    float* q_lds  = (float*)arena;       // refine overlay on A region [64c][64r]

    const int t   = threadIdx.x;
    const int l   = t & 63;
    const int w   = t >> 6;
    const int hi  = l >> 4;
    const int l15 = l & 15;
    const int n0  = blockIdx.x * TN;
    const int b   = n0 >> 10;
    const int hw0 = n0 & 1023;

    // ---- stage A once: bf16 rows, stride 528 shorts; coalesced x reads ----
    {
        const float* xp = x + (size_t)b * C_ * HW_ + hw0 + l;
        unsigned short* dst = AhU + l * 528;
#pragma unroll 8
        for (int j = 0; j < 64; ++j) {
            int c = w * 128 + 2 * j;
            float f0 = xp[(size_t)c * HW_];
            float f1 = xp[(size_t)(c + 1) * HW_];
            unsigned pk = (unsigned)f2bf(f0) | ((unsigned)f2bf(f1) << 16);
            *(unsigned*)&dst[c] = pk;
        }
    }

    const int srow = t >> 2;
    const int stq  = t & 3;
    float sv[K_]; int si[K_];
#pragma unroll
    for (int p = 0; p < K_; ++p) { sv[p] = NEG_INF; si[p] = 0x7fffffff; }

    uint4 breg[8];

    for (int tile = 0; tile < NTILE; ++tile) {
        // ---- stage chunk 0 into B0 (B region freed by prior scan barrier) ----
        {
            const uint4* p = (const uint4*)(membR + ((size_t)(0 * M_ + tile * TM) << 6)) + t;
#pragma unroll
            for (int i = 0; i < 8; ++i) breg[i] = p[i * 256];
#pragma unroll
            for (int i = 0; i < 8; ++i) {
                int item = i * 32 + (t >> 3);
                *(uint4*)(arena + B0_BASE + item * 128 + (((t & 7) << 4) ^ ((item & 7) << 4))) = breg[i];
            }
        }
        __syncthreads();

        f32x4 acc[4][4];
#pragma unroll
        for (int rf = 0; rf < 4; ++rf)
#pragma unroll
            for (int itf = 0; itf < 4; ++itf) acc[rf][itf] = (f32x4)0.f;

        int cur = 0;
        for (int kc = 0; kc < NKC; ++kc) {
            if (kc + 1 < NKC) {
                const uint4* p = (const uint4*)(membR + ((size_t)((kc + 1) * M_ + tile * TM) << 6)) + t;
#pragma unroll
                for (int i = 0; i < 8; ++i) breg[i] = p[i * 256];
            }
            const char* Bc = arena + (cur ? B1_BASE : B0_BASE);
#pragma unroll
            for (int sub = 0; sub < 2; ++sub) {
                short8 af[4], bf[4];
#pragma unroll
                for (int rf = 0; rf < 4; ++rf)
                    af[rf] = *(const short8*)(arena + (rf * 16 + l15) * AH_STRIDE +
                                              kc * 128 + sub * 64 + hi * 16);
#pragma unroll
                for (int itf = 0; itf < 4; ++itf) {
                    int item = w * 64 + itf * 16 + l15;
                    bf[itf] = *(const short8*)(Bc + item * 128 +
                                               ((sub * 64 + hi * 16) ^ ((l15 & 7) << 4)));
                }
#pragma unroll
                for (int rf = 0; rf < 4; ++rf)
#pragma unroll
                    for (int itf = 0; itf < 4; ++itf)
                        acc[rf][itf] = __builtin_amdgcn_mfma_f32_16x16x32_bf16(
                            af[rf], bf[itf], acc[rf][itf], 0, 0, 0);
            }
            if (kc + 1 < NKC) {
                char* Bn = arena + (cur ? B0_BASE : B1_BASE);
#pragma unroll
                for (int i = 0; i < 8; ++i) {
                    int item = i * 32 + (t >> 3);
                    *(uint4*)(Bn + item * 128 + (((t & 7) << 4) ^ ((item & 7) << 4))) = breg[i];
                }
            }
            __syncthreads();
            cur ^= 1;
        }

        // ---- dump att tile (overlays B region; all reads barrier-complete) ----
        const int m0 = tile * TM;
#pragma unroll
        for (int rf = 0; rf < 4; ++rf)
#pragma unroll
            for (int itf = 0; itf < 4; ++itf) {
                int col = w * 64 + itf * 16 + l15;
#pragma unroll
                for (int reg = 0; reg < 4; ++reg)
                    att[(rf * 16 + hi * 4 + reg) * ATT_STRIDE + col] = acc[rf][itf][reg];
            }
        __syncthreads();

        // ---- scan: 4 threads/row, running sorted top-8 ----
        for (int j = 0; j < 64; ++j) {
            int iloc = stq + 4 * j;
            float v = att[srow * ATT_STRIDE + iloc];
            if (v > sv[0]) {
                sv[0] = v; si[0] = m0 + iloc;
#pragma unroll
                for (int p = 0; p < K_ - 1; ++p) {
                    if (sv[p] > sv[p + 1]) {
                        float tv = sv[p]; sv[p] = sv[p + 1]; sv[p + 1] = tv;
                        int   ti = si[p]; si[p] = si[p + 1]; si[p + 1] = ti;
                    }
                }
            }
        }
        __syncthreads();
    }

    // ---- candidates ----
#pragma unroll
    for (int p = 0; p < K_; ++p) {
        candv[srow * 33 + stq * 8 + p] = sv[p];
        candi[srow * 33 + stq * 8 + p] = si[p];
    }
    __syncthreads();

    // ---- leader: 4-way merge -> approx top-16 ----
    if (t < TN) {
        const int row = t;
        int pos[4] = {7, 7, 7, 7};
        for (int s = 0; s < 16; ++s) {
            float vb = NEG_INF; int ib = 0x7fffffff; int qb = 0;
#pragma unroll
            for (int q = 0; q < 4; ++q) {
                if (pos[q] >= 0) {
                    float v = candv[row * 33 + q * 8 + pos[q]];
                    int  ii = candi[row * 33 + q * 8 + pos[q]];
                    if (v > vb || (v == vb && ii < ib)) { vb = v; ib = ii; qb = q; }
                }
            }
            selidx[row * 16 + s] = ib;
            --pos[qb];
        }
    }
    __syncthreads();

    // ---- exact fp32 refine of 16 candidates/row ----
    int cnd[4];
#pragma unroll
    for (int pp = 0; pp < 4; ++pp) cnd[pp] = selidx[t + 256 * pp];
    float racc[4] = {0.f, 0.f, 0.f, 0.f};
    for (int ch = 0; ch < 8; ++ch) {
        const int c0 = ch * 64;
        __syncthreads();
#pragma unroll
        for (int i = 0; i < 16; ++i) {
            int idx = t + 256 * i;
            int c = idx >> 6, r = idx & 63;
            q_lds[c * 64 + r] = x[(size_t)b * C_ * HW_ + (size_t)(c0 + c) * HW_ + hw0 + r];
        }
        __syncthreads();
#pragma unroll
        for (int pp = 0; pp < 4; ++pp) {
            const int row = (t + 256 * pp) >> 4;
            const float4* mp = (const float4*)(mempool + (size_t)cnd[pp] * C_ + c0);
            float a = racc[pp];
#pragma unroll
            for (int c4 = 0; c4 < 16; ++c4) {
                float4 m4 = mp[c4];
                a = fmaf(q_lds[(c4 * 4 + 0) * 64 + row], m4.x, a);
                a = fmaf(q_lds[(c4 * 4 + 1) * 64 + row], m4.y, a);
                a = fmaf(q_lds[(c4 * 4 + 2) * 64 + row], m4.z, a);
                a = fmaf(q_lds[(c4 * 4 + 3) * 64 + row], m4.w, a);
            }
            racc[pp] = a;
        }
    }
#pragma unroll
    for (int pp = 0; pp < 4; ++pp) refv[t + 256 * pp] = racc[pp];
    __syncthreads();

    // ---- leader: exact top-8 + softmax ----
    if (t < TN) {
        const int row = t;
        float rv[16]; int ri[16];
#pragma unroll
        for (int s = 0; s < 16; ++s) { rv[s] = refv[row * 16 + s]; ri[s] = selidx[row * 16 + s]; }
        float wv8[K_]; int wi8[K_];
#pragma unroll
        for (int sel = 0; sel < K_; ++sel) {
            float vb = NEG_INF; int ib = 0x7fffffff; int sb = 0;
            for (int s = 0; s < 16; ++s) {
                if (rv[s] > vb || (rv[s] == vb && ri[s] < ib)) { vb = rv[s]; ib = ri[s]; sb = s; }
            }
            rv[sb] = NEG_INF;
            wv8[sel] = vb; wi8[sel] = ib;
        }
        const float mx = wv8[0];
        float e[K_]; float sum = 0.f;
#pragma unroll
        for (int j = 0; j < K_; ++j) { e[j] = expf(wv8[j] - mx); sum += e[j]; }
        const float inv = 1.f / sum;
#pragma unroll
        for (int j = 0; j < K_; ++j) { w_lds[row * 8 + j] = e[j] * inv; i_lds[row * 8 + j] = wi8[j]; }
    }
    __syncthreads();

    // ---- combine: coalesced stores, gathered mempool reads ----
    const int crow = t & 63;
    const int cw   = t >> 6;
    float wreg[K_]; int ireg[K_];
#pragma unroll
    for (int j = 0; j < K_; ++j) { wreg[j] = w_lds[crow * 8 + j]; ireg[j] = i_lds[crow * 8 + j]; }
    float* outb = out + (size_t)b * C_ * HW_ + hw0 + crow;
#pragma unroll 2
    for (int cg = 0; cg < 32; ++cg) {
        const int c = cw * 128 + cg * 4;
        float o0 = 0.f, o1 = 0.f, o2 = 0.f, o3 = 0.f;
#pragma unroll
        for (int j = 0; j < K_; ++j) {
            const float4 mp4 = *(const float4*)&mempool[(size_t)ireg[j] * C_ + c];
            o0 = fmaf(wreg[j], mp4.x, o0);
            o1 = fmaf(wreg[j], mp4.y, o1);
            o2 = fmaf(wreg[j], mp4.z, o2);
            o3 = fmaf(wreg[j], mp4.w, o3);
        }
        outb[(size_t)(c + 0) * HW_] = o0;
        outb[(size_t)(c + 1) * HW_] = o1;
        outb[(size_t)(c + 2) * HW_] = o2;
        outb[(size_t)(c + 3) * HW_] = o3;
    }
}

extern "C" void kernel_launch(void* const* d_in, const int* in_sizes, int n_in,
                              void* d_out, int out_size, void* d_ws, size_t ws_size,
                              hipStream_t stream) {
    const float* x       = (const float*)d_in[0];
    const float* mempool = (const float*)d_in[1];
    unsigned short* membR = (unsigned short*)d_ws;   // 2 MiB
    float* o = (float*)d_out;
    convk<<<dim3(M_ * C_ / 1024), dim3(256), 0, stream>>>(mempool, membR);
    memk<<<dim3(512), dim3(256), 0, stream>>>(x, mempool, membR, o);
}

// Round 6
// 546.657 us; speedup vs baseline: 1.8222x; 1.3651x over previous
//
#include <hip/hip_runtime.h>

typedef __attribute__((ext_vector_type(4))) float f32x4;
typedef __attribute__((ext_vector_type(8))) short short8;

#define C_    512
#define HW_   1024
#define M_    2048
#define TN    32
#define NTILE 8
#define NKC   16
#define NCAND 16
#define NEG_INF (-1e30f)

// ---- LDS arena (bytes) ----
#define AH_STRIDE 1056                 // 528 bf16 per row (512 + 16 pad)
#define A_SIZE    (32 * 1056)          // 33792
#define B_BASE    A_SIZE
#define BBUF      16384                // 256 items x 64B bf16 (swizzled), dbuf
#define ATT_BASE  B_BASE               // att[32][260] f32 overlays B dbuf (+512 tail)
#define ATT_STRIDE 260
#define ARENA_SIZE (ATT_BASE + 32 * ATT_STRIDE * 4)   // 67072 -> 2 blocks/CU
// A-region overlays (dead post-GEMM): q_lds f32[64][32] @0 (refine);
//                                     w_lds[32][8] @10240; i_lds @11520
// ATT-region overlays (dead post-scan): candv[32][33] @+0; candi @+4352;
//                                       selidx[32][16] @+8704; refv @+10752

__device__ __forceinline__ unsigned short f2bf(float f) {
    unsigned u = __builtin_bit_cast(unsigned, f);
    u += 0x7fffu + ((u >> 16) & 1u);     // RNE
    return (unsigned short)(u >> 16);
}

__device__ __forceinline__ void gl_lds16(const void* g, void* l) {
    __builtin_amdgcn_global_load_lds(
        (const __attribute__((address_space(1))) unsigned int*)g,
        (__attribute__((address_space(3))) unsigned int*)l, 16, 0, 0);
}

// ---- repack mempool [2048][512] f32 -> membR bf16, kc-major (32ch), 16B-unit swizzle ----
__global__ __launch_bounds__(256) void convk(const float* __restrict__ in,
                                             unsigned short* __restrict__ ob) {
    int gid = blockIdx.x * 256 + threadIdx.x;       // 131072 threads, 8 ch each
    int m  = gid >> 6;
    int ug = gid & 63;                               // 8-channel unit
    const float4* p = (const float4*)(in + (size_t)m * C_ + ug * 8);
    float4 v0 = p[0], v1 = p[1];
    int4 o;
    o.x = (int)f2bf(v0.x) | ((int)f2bf(v0.y) << 16);
    o.y = (int)f2bf(v0.z) | ((int)f2bf(v0.w) << 16);
    o.z = (int)f2bf(v1.x) | ((int)f2bf(v1.y) << 16);
    o.w = (int)f2bf(v1.z) | ((int)f2bf(v1.w) << 16);
    int kc = ug >> 2, u = ug & 3;
    *(int4*)((char*)ob + (size_t)kc * 131072 + m * 64 + ((u ^ (m & 3)) << 4)) = o;
}

__global__ __launch_bounds__(256, 2) void memk(const float* __restrict__ x,
                                               const float* __restrict__ mempool,
                                               const unsigned short* __restrict__ membR,
                                               float* __restrict__ out) {
    __shared__ __align__(16) char arena[ARENA_SIZE];
    float* att    = (float*)(arena + ATT_BASE);
    float* candv  = (float*)(arena + ATT_BASE);             // [32][33]
    int*   candi  = (int*)(arena + ATT_BASE + 4352);        // [32][33]
    int*   selidx = (int*)(arena + ATT_BASE + 8704);        // [32][16]
    float* refv   = (float*)(arena + ATT_BASE + 10752);     // [32][16]
    float* q_lds  = (float*)arena;                          // refine overlay [64c][32r]
    float* w_lds  = (float*)(arena + 10240);                // [32][8]
    int*   i_lds  = (int*)(arena + 11520);                  // [32][8]

    const int t   = threadIdx.x;
    const int l   = t & 63;
    const int w   = t >> 6;
    const int hi  = l >> 4;
    const int l15 = l & 15;
    const int n0  = blockIdx.x * TN;
    const int b   = n0 >> 10;
    const int hw0 = n0 & 1023;
    const float* xb = x + (size_t)b * C_ * HW_ + hw0;

    // ---- stage A once: x -> bf16 rows, stride 528 shorts ----
    {
        const int row = t & 31, g = t >> 5;
        const float* xp = xb + row;
        char* Arow = arena + row * AH_STRIDE;
#pragma unroll 8
        for (int j = 0; j < 32; ++j) {
            int c = g * 64 + 2 * j;
            float f0 = xp[(size_t)c * HW_];
            float f1 = xp[(size_t)(c + 1) * HW_];
            unsigned pk = (unsigned)f2bf(f0) | ((unsigned)f2bf(f1) << 16);
            *(unsigned*)(Arow + c * 2) = pk;
        }
    }

    // per-thread running top-8 (ascending), 4 threads/row (t<128 scan)
    const int srow = t >> 2, stq = t & 3;
    float sv[8]; int si[8];
#pragma unroll
    for (int p = 0; p < 8; ++p) { sv[p] = NEG_INF; si[p] = 0x7fffffff; }

    const char* Ab0 = arena + l15 * AH_STRIDE;
    const char* Ab1 = arena + (16 + l15) * AH_STRIDE;
    const int hio = hi << 4;
    int bOff[4];
#pragma unroll
    for (int itf = 0; itf < 4; ++itf)
        bOff[itf] = (w * 64 + itf * 16 + l15) * 64 + ((hi ^ (l15 & 3)) << 4);

    for (int tile = 0; tile < NTILE; ++tile) {
        // ---- restage kc0 into buf0 (B region freed by prior scan barrier) ----
        {
            const char* base = (const char*)membR + tile * 16384 + w * 4096;
            char* dst = arena + B_BASE + w * 4096;
#pragma unroll
            for (int j = 0; j < 4; ++j)
                gl_lds16(base + j * 1024 + (l << 4), dst + j * 1024);
        }
        __syncthreads();

        f32x4 acc[2][4];
#pragma unroll
        for (int rf = 0; rf < 2; ++rf)
#pragma unroll
            for (int itf = 0; itf < 4; ++itf) acc[rf][itf] = (f32x4)0.f;

        for (int kc = 0; kc < NKC; ++kc) {
            int cur = kc & 1;
            if (kc + 1 < NKC) {
                const char* base = (const char*)membR + (size_t)(kc + 1) * 131072 +
                                   tile * 16384 + w * 4096;
                char* dst = arena + B_BASE + (cur ^ 1) * BBUF + w * 4096;
#pragma unroll
                for (int j = 0; j < 4; ++j)
                    gl_lds16(base + j * 1024 + (l << 4), dst + j * 1024);
            }
            const char* Bc = arena + B_BASE + cur * BBUF;
            short8 a0 = *(const short8*)(Ab0 + kc * 64 + hio);
            short8 a1 = *(const short8*)(Ab1 + kc * 64 + hio);
            short8 bv[4];
#pragma unroll
            for (int itf = 0; itf < 4; ++itf) bv[itf] = *(const short8*)(Bc + bOff[itf]);
#pragma unroll
            for (int itf = 0; itf < 4; ++itf) {
                acc[0][itf] = __builtin_amdgcn_mfma_f32_16x16x32_bf16(a0, bv[itf], acc[0][itf], 0, 0, 0);
                acc[1][itf] = __builtin_amdgcn_mfma_f32_16x16x32_bf16(a1, bv[itf], acc[1][itf], 0, 0, 0);
            }
            __syncthreads();
        }

        // ---- dump att [32][260] ----
#pragma unroll
        for (int rf = 0; rf < 2; ++rf)
#pragma unroll
            for (int itf = 0; itf < 4; ++itf) {
                int col = w * 64 + itf * 16 + l15;
#pragma unroll
                for (int reg = 0; reg < 4; ++reg)
                    att[(rf * 16 + hi * 4 + reg) * ATT_STRIDE + col] = acc[rf][itf][reg];
            }
        __syncthreads();

        // ---- scan (R3-proven): 4 threads/row, t<128 ----
        const int m0 = tile * 256;
        if (t < 128) {
            for (int j = 0; j < 64; ++j) {
                int iloc = stq + 4 * j;
                float v = att[srow * ATT_STRIDE + iloc];
                if (v > sv[0]) {
                    sv[0] = v; si[0] = m0 + iloc;
#pragma unroll
                    for (int p = 0; p < 7; ++p) {
                        if (sv[p] > sv[p + 1]) {
                            float tv = sv[p]; sv[p] = sv[p + 1]; sv[p + 1] = tv;
                            int   ti = si[p]; si[p] = si[p + 1]; si[p + 1] = ti;
                        }
                    }
                }
            }
        }
        __syncthreads();   // scans done before next restage / candv overlay
    }

    // ---- candidates: [row][33] (R3 layout) ----
    if (t < 128) {
#pragma unroll
        for (int p = 0; p < 8; ++p) {
            candv[srow * 33 + stq * 8 + p] = sv[p];
            candi[srow * 33 + stq * 8 + p] = si[p];
        }
    }
    __syncthreads();

    // ---- leader: 4-way merge of sorted lists -> approx top-16 (R3-proven) ----
    if (t < TN) {
        const int row = t;
        int pos[4] = {7, 7, 7, 7};
        for (int s = 0; s < NCAND; ++s) {
            float vb = NEG_INF; int ib = 0x7fffffff; int qb = 0;
#pragma unroll
            for (int q = 0; q < 4; ++q) {
                if (pos[q] >= 0) {
                    float v = candv[row * 33 + q * 8 + pos[q]];
                    int  ii = candi[row * 33 + q * 8 + pos[q]];
                    if (v > vb || (v == vb && ii < ib)) { vb = v; ib = ii; qb = q; }
                }
            }
            selidx[row * NCAND + s] = ib;
#pragma unroll
            for (int q = 0; q < 4; ++q) if (q == qb) --pos[q];
        }
    }
    __syncthreads();

    // ---- exact fp32 refine (R3-proven): pair p = t + 256*pp, row=p>>4, slot=p&15 ----
    int cnd[2];
    cnd[0] = selidx[t];
    cnd[1] = selidx[t + 256];
    float racc[2] = {0.f, 0.f};
    for (int ch = 0; ch < 8; ++ch) {
        const int c0 = ch * 64;
        __syncthreads();
#pragma unroll
        for (int i = 0; i < 8; ++i) {
            int idx = t + 256 * i;
            int c = idx >> 5, r = idx & 31;
            q_lds[c * 32 + r] = xb[(size_t)(c0 + c) * HW_ + r];
        }
        __syncthreads();
#pragma unroll
        for (int pp = 0; pp < 2; ++pp) {
            const int row = (t + 256 * pp) >> 4;
            const float4* mp = (const float4*)(mempool + (size_t)cnd[pp] * C_ + c0);
            float a = racc[pp];
#pragma unroll
            for (int c4 = 0; c4 < 16; ++c4) {
                float4 m4 = mp[c4];
                a = fmaf(q_lds[(c4 * 4 + 0) * 32 + row], m4.x, a);
                a = fmaf(q_lds[(c4 * 4 + 1) * 32 + row], m4.y, a);
                a = fmaf(q_lds[(c4 * 4 + 2) * 32 + row], m4.z, a);
                a = fmaf(q_lds[(c4 * 4 + 3) * 32 + row], m4.w, a);
            }
            racc[pp] = a;
        }
    }
    refv[t] = racc[0];
    refv[t + 256] = racc[1];
    __syncthreads();

    // ---- leader: exact top-8 of 16 + softmax (R3-proven marking version) ----
    if (t < TN) {
        const int row = t;
        float rv[16]; int ri[16];
#pragma unroll
        for (int s = 0; s < 16; ++s) { rv[s] = refv[row * 16 + s]; ri[s] = selidx[row * 16 + s]; }
        float wv8[8]; int wi8[8];
#pragma unroll
        for (int sel = 0; sel < 8; ++sel) {
            float vb = NEG_INF; int ib = 0x7fffffff; int sb = 0;
            for (int s = 0; s < 16; ++s) {
                if (rv[s] > vb || (rv[s] == vb && ri[s] < ib)) { vb = rv[s]; ib = ri[s]; sb = s; }
            }
            rv[sb] = NEG_INF;
            wv8[sel] = vb; wi8[sel] = ib;
        }
        const float mx = wv8[0];
        float e[8]; float sum = 0.f;
#pragma unroll
        for (int j = 0; j < 8; ++j) { e[j] = expf(wv8[j] - mx); sum += e[j]; }
        const float inv = 1.f / sum;
#pragma unroll
        for (int j = 0; j < 8; ++j) { w_lds[row * 8 + j] = e[j] * inv; i_lds[row * 8 + j] = wi8[j]; }
    }
    __syncthreads();

    // ---- combine (R3-proven): gathered mempool float4, strided stores ----
    const int crow = t & 31;
    const int cw   = t >> 5;      // 0..7, 64 channels each
    float wreg[8]; int ireg[8];
#pragma unroll
    for (int j = 0; j < 8; ++j) { wreg[j] = w_lds[crow * 8 + j]; ireg[j] = i_lds[crow * 8 + j]; }
    float* outb = out + (size_t)b * C_ * HW_ + hw0 + crow;
#pragma unroll 2
    for (int cg = 0; cg < 16; ++cg) {
        const int c = cw * 64 + cg * 4;
        float o0 = 0.f, o1 = 0.f, o2 = 0.f, o3 = 0.f;
#pragma unroll
        for (int j = 0; j < 8; ++j) {
            const float4 mp4 = *(const float4*)&mempool[(size_t)ireg[j] * C_ + c];
            o0 = fmaf(wreg[j], mp4.x, o0);
            o1 = fmaf(wreg[j], mp4.y, o1);
            o2 = fmaf(wreg[j], mp4.z, o2);
            o3 = fmaf(wreg[j], mp4.w, o3);
        }
        outb[(size_t)(c + 0) * HW_] = o0;
        outb[(size_t)(c + 1) * HW_] = o1;
        outb[(size_t)(c + 2) * HW_] = o2;
        outb[(size_t)(c + 3) * HW_] = o3;
    }
}

extern "C" void kernel_launch(void* const* d_in, const int* in_sizes, int n_in,
                              void* d_out, int out_size, void* d_ws, size_t ws_size,
                              hipStream_t stream) {
    const float* x       = (const float*)d_in[0];
    const float* mempool = (const float*)d_in[1];
    unsigned short* membR = (unsigned short*)d_ws;   // 2 MiB bf16 repack
    float* o = (float*)d_out;
    convk<<<dim3(512), dim3(256), 0, stream>>>(mempool, membR);
    memk<<<dim3(1024), dim3(256), 0, stream>>>(x, mempool, membR, o);
}

// Round 7
// 521.775 us; speedup vs baseline: 1.9090x; 1.0477x over previous
//
#include <hip/hip_runtime.h>

typedef __attribute__((ext_vector_type(4))) float f32x4;
typedef __attribute__((ext_vector_type(8))) short short8;

#define C_    512
#define HW_   1024
#define M_    2048
#define TN    32
#define NTILE 8
#define NKC   16
#define NCAND 16
#define NEG_INF (-1e30f)

// ---- LDS arena (bytes) ----
#define ATT_BASE   32768               // A bf16 [32][1024B] XOR-swizzled @0
#define ATT_STRIDE 264                 // bf16 elements per row (256 + 8 pad)
#define ARENA_SIZE (ATT_BASE + 32 * ATT_STRIDE * 2)   // 49664 -> 3 blocks/CU
// A-region overlays (dead post-GEMM): q_lds f32[64][32] @0; w_lds @8192; i_lds @9216
// ATT-region overlays (dead post-scan): candv[32][33] @+0; candi @+4224;
//                                       selidx[32][16] @+8448; refv @+10496

__device__ __forceinline__ unsigned short f2bf(float f) {
    unsigned u = __builtin_bit_cast(unsigned, f);
    u += 0x7fffu + ((u >> 16) & 1u);     // RNE
    return (unsigned short)(u >> 16);
}
__device__ __forceinline__ float bf2f(unsigned short s) {
    return __builtin_bit_cast(float, (unsigned)s << 16);
}

// ---- repack mempool [2048][512] f32 -> membR bf16, kc-major (32ch chunks) ----
__global__ __launch_bounds__(256) void convk(const float* __restrict__ in,
                                             unsigned short* __restrict__ ob) {
    int gid = blockIdx.x * 256 + threadIdx.x;       // 131072 threads, 8 ch each
    int m  = gid >> 6;
    int ug = gid & 63;                               // 8-channel unit
    const float4* p = (const float4*)(in + (size_t)m * C_ + ug * 8);
    float4 v0 = p[0], v1 = p[1];
    int4 o;
    o.x = (int)f2bf(v0.x) | ((int)f2bf(v0.y) << 16);
    o.y = (int)f2bf(v0.z) | ((int)f2bf(v0.w) << 16);
    o.z = (int)f2bf(v1.x) | ((int)f2bf(v1.y) << 16);
    o.w = (int)f2bf(v1.z) | ((int)f2bf(v1.w) << 16);
    int kc = ug >> 2, u = ug & 3;
    *(int4*)((char*)ob + (size_t)kc * 131072 + m * 64 + (u << 4)) = o;
}

__global__ __launch_bounds__(256, 3) void memk(const float* __restrict__ x,
                                               const float* __restrict__ mempool,
                                               const unsigned short* __restrict__ membR,
                                               float* __restrict__ out) {
    __shared__ __align__(16) char arena[ARENA_SIZE];
    unsigned short* att16 = (unsigned short*)(arena + ATT_BASE);
    float* candv  = (float*)(arena + ATT_BASE);             // [32][33]
    int*   candi  = (int*)(arena + ATT_BASE + 4224);        // [32][33]
    int*   selidx = (int*)(arena + ATT_BASE + 8448);        // [32][16]
    float* refv   = (float*)(arena + ATT_BASE + 10496);     // [32][16]
    float* q_lds  = (float*)arena;                          // refine overlay [64c][32r]
    float* w_lds  = (float*)(arena + 8192);                 // [32][8]
    int*   i_lds  = (int*)(arena + 9216);                   // [32][8]

    const int t   = threadIdx.x;
    const int l   = t & 63;
    const int w   = t >> 6;
    const int hi  = l >> 4;
    const int l15 = l & 15;
    const int n0  = blockIdx.x * TN;
    const int b   = n0 >> 10;
    const int hw0 = n0 & 1023;
    const float* xb = x + (size_t)b * C_ * HW_ + hw0;

    // ---- stage A once: x -> bf16, rows of 1024B, 16B-unit XOR swizzle by row ----
    {
        const int row = t & 31, g = t >> 5;
        const float* xp = xb + row;
        char* Arow = arena + row * 1024;
        const int swz = (row & 7) << 4;
#pragma unroll 8
        for (int j = 0; j < 32; ++j) {
            int c = g * 64 + 2 * j;
            float f0 = xp[(size_t)c * HW_];
            float f1 = xp[(size_t)(c + 1) * HW_];
            unsigned pk = (unsigned)f2bf(f0) | ((unsigned)f2bf(f1) << 16);
            *(unsigned*)(Arow + ((2 * c) ^ swz)) = pk;
        }
    }
    __syncthreads();

    // per-thread running top-8 (ascending), 4 threads/row (t<128 scan)
    const int srow = t >> 2, stq = t & 3;
    float sv[8]; int si[8];
#pragma unroll
    for (int p = 0; p < 8; ++p) { sv[p] = NEG_INF; si[p] = 0x7fffffff; }

    const int aswz = (l15 & 7) << 4;
    const char* Ab0 = arena + l15 * 1024;
    const char* Ab1 = arena + (16 + l15) * 1024;
    // per-lane B fragment base: item = tile*256 + w*64 + itf*16 + l15, bytes hi*16
    const char* bbase = (const char*)membR + w * 4096 + l15 * 64 + hi * 16;

    // prefetch (tile0, kc0)
    short8 bq[4];
#pragma unroll
    for (int itf = 0; itf < 4; ++itf) bq[itf] = *(const short8*)(bbase + itf * 1024);

    for (int tile = 0; tile < NTILE; ++tile) {
        f32x4 acc[2][4];
#pragma unroll
        for (int rf = 0; rf < 2; ++rf)
#pragma unroll
            for (int itf = 0; itf < 4; ++itf) acc[rf][itf] = (f32x4)0.f;

#pragma unroll 2
        for (int kc = 0; kc < NKC; ++kc) {
            // prefetch next fragment set (next kc, or next tile's kc0)
            short8 bn[4];
            {
                int nt = tile, nk = kc + 1;
                if (nk == NKC) { nk = 0; ++nt; }
                size_t off = (nt < NTILE) ? ((size_t)nk * 131072 + (size_t)nt * 16384) : 0;
                const char* p = bbase + off;
#pragma unroll
                for (int itf = 0; itf < 4; ++itf) bn[itf] = *(const short8*)(p + itf * 1024);
            }
            const int ao = (kc * 64 + (hi << 4)) ^ aswz;
            short8 a0 = *(const short8*)(Ab0 + ao);
            short8 a1 = *(const short8*)(Ab1 + ao);
#pragma unroll
            for (int itf = 0; itf < 4; ++itf) {
                acc[0][itf] = __builtin_amdgcn_mfma_f32_16x16x32_bf16(a0, bq[itf], acc[0][itf], 0, 0, 0);
                acc[1][itf] = __builtin_amdgcn_mfma_f32_16x16x32_bf16(a1, bq[itf], acc[1][itf], 0, 0, 0);
            }
#pragma unroll
            for (int itf = 0; itf < 4; ++itf) bq[itf] = bn[itf];
        }

        // ---- dump att bf16 [32][264] ----
#pragma unroll
        for (int rf = 0; rf < 2; ++rf)
#pragma unroll
            for (int itf = 0; itf < 4; ++itf) {
                int col = w * 64 + itf * 16 + l15;
#pragma unroll
                for (int reg = 0; reg < 4; ++reg)
                    att16[(rf * 16 + hi * 4 + reg) * ATT_STRIDE + col] = f2bf(acc[rf][itf][reg]);
            }
        __syncthreads();

        // ---- scan: 4 threads/row, t<128 ----
        const int m0 = tile * 256;
        if (t < 128) {
            for (int j = 0; j < 64; ++j) {
                int iloc = stq + 4 * j;
                float v = bf2f(att16[srow * ATT_STRIDE + iloc]);
                if (v > sv[0]) {
                    sv[0] = v; si[0] = m0 + iloc;
#pragma unroll
                    for (int p = 0; p < 7; ++p) {
                        if (sv[p] > sv[p + 1]) {
                            float tv = sv[p]; sv[p] = sv[p + 1]; sv[p + 1] = tv;
                            int   ti = si[p]; si[p] = si[p + 1]; si[p + 1] = ti;
                        }
                    }
                }
            }
        }
        __syncthreads();   // scans done before next dump / candv overlay
    }

    // ---- candidates: [row][33] ----
    if (t < 128) {
#pragma unroll
        for (int p = 0; p < 8; ++p) {
            candv[srow * 33 + stq * 8 + p] = sv[p];
            candi[srow * 33 + stq * 8 + p] = si[p];
        }
    }
    __syncthreads();

    // ---- leader: 4-way merge of sorted lists -> approx top-16 ----
    if (t < TN) {
        const int row = t;
        int pos[4] = {7, 7, 7, 7};
        for (int s = 0; s < NCAND; ++s) {
            float vb = NEG_INF; int ib = 0x7fffffff; int qb = 0;
#pragma unroll
            for (int q = 0; q < 4; ++q) {
                if (pos[q] >= 0) {
                    float v = candv[row * 33 + q * 8 + pos[q]];
                    int  ii = candi[row * 33 + q * 8 + pos[q]];
                    if (v > vb || (v == vb && ii < ib)) { vb = v; ib = ii; qb = q; }
                }
            }
            selidx[row * NCAND + s] = ib;
#pragma unroll
            for (int q = 0; q < 4; ++q) if (q == qb) --pos[q];
        }
    }
    __syncthreads();

    // ---- exact fp32 refine: pair p = t + 256*pp, row=p>>4, slot=p&15 ----
    int cnd[2];
    cnd[0] = selidx[t];
    cnd[1] = selidx[t + 256];
    float racc[2] = {0.f, 0.f};
    for (int ch = 0; ch < 8; ++ch) {
        const int c0 = ch * 64;
        __syncthreads();
#pragma unroll
        for (int i = 0; i < 8; ++i) {
            int idx = t + 256 * i;
            int c = idx >> 5, r = idx & 31;
            q_lds[c * 32 + r] = xb[(size_t)(c0 + c) * HW_ + r];
        }
        __syncthreads();
#pragma unroll
        for (int pp = 0; pp < 2; ++pp) {
            const int row = (t + 256 * pp) >> 4;
            const float4* mp = (const float4*)(mempool + (size_t)cnd[pp] * C_ + c0);
            float a = racc[pp];
#pragma unroll
            for (int c4 = 0; c4 < 16; ++c4) {
                float4 m4 = mp[c4];
                a = fmaf(q_lds[(c4 * 4 + 0) * 32 + row], m4.x, a);
                a = fmaf(q_lds[(c4 * 4 + 1) * 32 + row], m4.y, a);
                a = fmaf(q_lds[(c4 * 4 + 2) * 32 + row], m4.z, a);
                a = fmaf(q_lds[(c4 * 4 + 3) * 32 + row], m4.w, a);
            }
            racc[pp] = a;
        }
    }
    refv[t] = racc[0];
    refv[t + 256] = racc[1];
    __syncthreads();

    // ---- leader: exact top-8 of 16 + softmax ----
    if (t < TN) {
        const int row = t;
        float rv[16]; int ri[16];
#pragma unroll
        for (int s = 0; s < 16; ++s) { rv[s] = refv[row * 16 + s]; ri[s] = selidx[row * 16 + s]; }
        float wv8[8]; int wi8[8];
#pragma unroll
        for (int sel = 0; sel < 8; ++sel) {
            float vb = NEG_INF; int ib = 0x7fffffff; int sb = 0;
            for (int s = 0; s < 16; ++s) {
                if (rv[s] > vb || (rv[s] == vb && ri[s] < ib)) { vb = rv[s]; ib = ri[s]; sb = s; }
            }
            rv[sb] = NEG_INF;
            wv8[sel] = vb; wi8[sel] = ib;
        }
        const float mx = wv8[0];
        float e[8]; float sum = 0.f;
#pragma unroll
        for (int j = 0; j < 8; ++j) { e[j] = expf(wv8[j] - mx); sum += e[j]; }
        const float inv = 1.f / sum;
#pragma unroll
        for (int j = 0; j < 8; ++j) { w_lds[row * 8 + j] = e[j] * inv; i_lds[row * 8 + j] = wi8[j]; }
    }
    __syncthreads();

    // ---- combine: gathered mempool float4, strided stores ----
    const int crow = t & 31;
    const int cw   = t >> 5;      // 0..7, 64 channels each
    float wreg[8]; int ireg[8];
#pragma unroll
    for (int j = 0; j < 8; ++j) { wreg[j] = w_lds[crow * 8 + j]; ireg[j] = i_lds[crow * 8 + j]; }
    float* outb = out + (size_t)b * C_ * HW_ + hw0 + crow;
#pragma unroll 2
    for (int cg = 0; cg < 16; ++cg) {
        const int c = cw * 64 + cg * 4;
        float o0 = 0.f, o1 = 0.f, o2 = 0.f, o3 = 0.f;
#pragma unroll
        for (int j = 0; j < 8; ++j) {
            const float4 mp4 = *(const float4*)&mempool[(size_t)ireg[j] * C_ + c];
            o0 = fmaf(wreg[j], mp4.x, o0);
            o1 = fmaf(wreg[j], mp4.y, o1);
            o2 = fmaf(wreg[j], mp4.z, o2);
            o3 = fmaf(wreg[j], mp4.w, o3);
        }
        outb[(size_t)(c + 0) * HW_] = o0;
        outb[(size_t)(c + 1) * HW_] = o1;
        outb[(size_t)(c + 2) * HW_] = o2;
        outb[(size_t)(c + 3) * HW_] = o3;
    }
}

extern "C" void kernel_launch(void* const* d_in, const int* in_sizes, int n_in,
                              void* d_out, int out_size, void* d_ws, size_t ws_size,
                              hipStream_t stream) {
    const float* x       = (const float*)d_in[0];
    const float* mempool = (const float*)d_in[1];
    unsigned short* membR = (unsigned short*)d_ws;   // 2 MiB bf16 repack
    float* o = (float*)d_out;
    convk<<<dim3(512), dim3(256), 0, stream>>>(mempool, membR);
    memk<<<dim3(1024), dim3(256), 0, stream>>>(x, mempool, membR, o);
}

// Round 8
// 443.955 us; speedup vs baseline: 2.2437x; 1.1753x over previous
//
#include <hip/hip_runtime.h>

typedef __attribute__((ext_vector_type(4))) float f32x4;
typedef __attribute__((ext_vector_type(8))) short short8;

#define C_    512
#define HW_   1024
#define M_    2048
#define TN    32
#define NTILE 8
#define NKC   16
#define NSTEP (NTILE * NKC)
#define NCAND 16
#define NEG_INF (-1e30f)

// ---- LDS arena (bytes) ----
#define ATT_BASE   32768               // A bf16 [32][1024B] XOR-swizzled @0
#define ATT_STRIDE 264                 // bf16 elements per row (256 + 8 pad)
#define ARENA_SIZE 49664               // -> 3 blocks/CU
// overlays:
//  [0,32768)   A (GEMM) -> q fp32 [32][260] (refine, spills to 33280) ; w_lds@8192 i_lds@9216 (post-refine)
//  [32768,..)  att16 -> candv[32][33]@32768, candi@36992, selidx@41216, refv@43264
#define CV_BASE  32768
#define CI_BASE  36992
#define SEL_BASE 41216
#define RFV_BASE 43264
#define QS 260                          // refine q row stride (f32)

__device__ __forceinline__ unsigned short f2bf(float f) {
    unsigned u = __builtin_bit_cast(unsigned, f);
    u += 0x7fffu + ((u >> 16) & 1u);     // RNE
    return (unsigned short)(u >> 16);
}
__device__ __forceinline__ float bf2f(unsigned short s) {
    return __builtin_bit_cast(float, (unsigned)s << 16);
}

// ---- repack mempool [2048][512] f32 -> membR bf16, kc-major (32ch chunks) ----
__global__ __launch_bounds__(256) void convk(const float* __restrict__ in,
                                             unsigned short* __restrict__ ob) {
    int gid = blockIdx.x * 256 + threadIdx.x;
    int m  = gid >> 6;
    int ug = gid & 63;
    const float4* p = (const float4*)(in + (size_t)m * C_ + ug * 8);
    float4 v0 = p[0], v1 = p[1];
    int4 o;
    o.x = (int)f2bf(v0.x) | ((int)f2bf(v0.y) << 16);
    o.y = (int)f2bf(v0.z) | ((int)f2bf(v0.w) << 16);
    o.z = (int)f2bf(v1.x) | ((int)f2bf(v1.y) << 16);
    o.w = (int)f2bf(v1.z) | ((int)f2bf(v1.w) << 16);
    int kc = ug >> 2, u = ug & 3;
    *(int4*)((char*)ob + (size_t)kc * 131072 + m * 64 + (u << 4)) = o;
}

__global__ __launch_bounds__(256, 3) void memk(const float* __restrict__ x,
                                               const float* __restrict__ mempool,
                                               const unsigned short* __restrict__ membR,
                                               float* __restrict__ out) {
    __shared__ __align__(16) char arena[ARENA_SIZE];
    unsigned short* att16 = (unsigned short*)(arena + ATT_BASE);
    float* candv  = (float*)(arena + CV_BASE);              // [32][33]
    int*   candi  = (int*)(arena + CI_BASE);                // [32][33]
    int*   selidx = (int*)(arena + SEL_BASE);               // [32][16]
    float* refv   = (float*)(arena + RFV_BASE);             // [32][16]
    float* qs     = (float*)arena;                          // refine [32][260]
    float* w_lds  = (float*)(arena + 8192);                 // [32][8]
    int*   i_lds  = (int*)(arena + 9216);                   // [32][8]

    const int t   = threadIdx.x;
    const int l   = t & 63;
    const int w   = t >> 6;
    const int hi  = l >> 4;
    const int l15 = l & 15;
    const int n0  = blockIdx.x * TN;
    const int b   = n0 >> 10;
    const int hw0 = n0 & 1023;
    const float* xb = x + (size_t)b * C_ * HW_ + hw0;

    // ---- stage A once: x -> bf16, rows of 1024B, 16B-unit XOR swizzle by row ----
    {
        const int row = t & 31, g = t >> 5;
        const float* xp = xb + row;
        char* Arow = arena + row * 1024;
        const int swz = (row & 7) << 4;
#pragma unroll 8
        for (int j = 0; j < 32; ++j) {
            int c = g * 64 + 2 * j;
            float f0 = xp[(size_t)c * HW_];
            float f1 = xp[(size_t)(c + 1) * HW_];
            unsigned pk = (unsigned)f2bf(f0) | ((unsigned)f2bf(f1) << 16);
            *(unsigned*)(Arow + ((2 * c) ^ swz)) = pk;
        }
    }
    __syncthreads();

    // per-thread running top-8 (ascending), 4 threads/row (t<128 scan)
    const int srow = t >> 2, stq = t & 3;
    float sv[8]; int si[8];
#pragma unroll
    for (int p = 0; p < 8; ++p) { sv[p] = NEG_INF; si[p] = 0x7fffffff; }

    const int aswz = (l15 & 7) << 4;
    const char* Ab0 = arena + l15 * 1024;
    const char* Ab1 = arena + (16 + l15) * 1024;
    const int hio = hi << 4;
    // per-lane B fragment base: item = tile*256 + w*64 + itf*16 + l15, bytes hi*16
    const char* bbase = (const char*)membR + w * 4096 + l15 * 64 + hi * 16;

    // depth-2 B prefetch pipeline over linear steps s = tile*16+kc
    short8 bq[4], bp[4];
    {
        const char* p0 = bbase;                       // s=0
        const char* p1 = bbase + 131072;              // s=1 (kc=1)
#pragma unroll
        for (int itf = 0; itf < 4; ++itf) {
            bq[itf] = *(const short8*)(p0 + itf * 1024);
            bp[itf] = *(const short8*)(p1 + itf * 1024);
        }
    }

    for (int tile = 0; tile < NTILE; ++tile) {
        f32x4 acc[2][4];
#pragma unroll
        for (int rf = 0; rf < 2; ++rf)
#pragma unroll
            for (int itf = 0; itf < 4; ++itf) acc[rf][itf] = (f32x4)0.f;

#pragma unroll 4
        for (int kc = 0; kc < NKC; ++kc) {
            // prefetch step s+2 (clamped; extra load harmless)
            int s = tile * NKC + kc + 2;
            int sc = (s < NSTEP) ? s : 0;
            const char* pn = bbase + (size_t)(sc & 15) * 131072 + (size_t)(sc >> 4) * 16384;
            short8 bn[4];
#pragma unroll
            for (int itf = 0; itf < 4; ++itf) bn[itf] = *(const short8*)(pn + itf * 1024);

            const int ao = (kc * 64 + hio) ^ aswz;
            short8 a0 = *(const short8*)(Ab0 + ao);
            short8 a1 = *(const short8*)(Ab1 + ao);
#pragma unroll
            for (int itf = 0; itf < 4; ++itf) {
                acc[0][itf] = __builtin_amdgcn_mfma_f32_16x16x32_bf16(a0, bq[itf], acc[0][itf], 0, 0, 0);
                acc[1][itf] = __builtin_amdgcn_mfma_f32_16x16x32_bf16(a1, bq[itf], acc[1][itf], 0, 0, 0);
            }
#pragma unroll
            for (int itf = 0; itf < 4; ++itf) { bq[itf] = bp[itf]; bp[itf] = bn[itf]; }
        }

        // ---- dump att bf16 [32][264] ----
#pragma unroll
        for (int rf = 0; rf < 2; ++rf)
#pragma unroll
            for (int itf = 0; itf < 4; ++itf) {
                int col = w * 64 + itf * 16 + l15;
#pragma unroll
                for (int reg = 0; reg < 4; ++reg)
                    att16[(rf * 16 + hi * 4 + reg) * ATT_STRIDE + col] = f2bf(acc[rf][itf][reg]);
            }
        __syncthreads();

        // ---- scan: 4 threads/row, vectorized short8 reads + max-prune ----
        const int m0 = tile * 256;
        if (t < 128) {
            const unsigned short* arow = att16 + srow * ATT_STRIDE;
#pragma unroll
            for (int v = 0; v < 8; ++v) {
                short8 pv = *(const short8*)(arow + stq * 8 + v * 32);
                float f[8];
#pragma unroll
                for (int e = 0; e < 8; ++e) f[e] = bf2f((unsigned short)pv[e]);
                float m01 = fmaxf(f[0], f[1]), m23 = fmaxf(f[2], f[3]);
                float m45 = fmaxf(f[4], f[5]), m67 = fmaxf(f[6], f[7]);
                float vmax = fmaxf(fmaxf(m01, m23), fmaxf(m45, m67));
                if (vmax > sv[0]) {
#pragma unroll
                    for (int e = 0; e < 8; ++e) {
                        if (f[e] > sv[0]) {
                            sv[0] = f[e]; si[0] = m0 + stq * 8 + v * 32 + e;
#pragma unroll
                            for (int p = 0; p < 7; ++p) {
                                if (sv[p] > sv[p + 1]) {
                                    float tv = sv[p]; sv[p] = sv[p + 1]; sv[p + 1] = tv;
                                    int   ti = si[p]; si[p] = si[p + 1]; si[p + 1] = ti;
                                }
                            }
                        }
                    }
                }
            }
        }
        __syncthreads();   // scans done before next dump / candv overlay
    }

    // ---- candidates: [row][33] ----
    if (t < 128) {
#pragma unroll
        for (int p = 0; p < 8; ++p) {
            candv[srow * 33 + stq * 8 + p] = sv[p];
            candi[srow * 33 + stq * 8 + p] = si[p];
        }
    }
    __syncthreads();

    // ---- leader: 4-way merge of sorted lists -> approx top-16 ----
    if (t < TN) {
        const int row = t;
        int pos[4] = {7, 7, 7, 7};
        for (int s = 0; s < NCAND; ++s) {
            float vb = NEG_INF; int ib = 0x7fffffff; int qb = 0;
#pragma unroll
            for (int q = 0; q < 4; ++q) {
                if (pos[q] >= 0) {
                    float v = candv[row * 33 + q * 8 + pos[q]];
                    int  ii = candi[row * 33 + q * 8 + pos[q]];
                    if (v > vb || (v == vb && ii < ib)) { vb = v; ib = ii; qb = q; }
                }
            }
            selidx[row * NCAND + s] = ib;
#pragma unroll
            for (int q = 0; q < 4; ++q) if (q == qb) --pos[q];
        }
    }
    __syncthreads();

    // ---- exact fp32 refine: pair p = t + 256*pp, row=p>>4, slot=p&15; 2 chunks ----
    int cnd[2];
    cnd[0] = selidx[t];
    cnd[1] = selidx[t + 256];
    float racc[2] = {0.f, 0.f};
#pragma unroll
    for (int ch = 0; ch < 2; ++ch) {
        const int c0 = ch * 256;
        __syncthreads();               // prior q reads / merge done
        {
            const int r = t & 31, g = t >> 5;
            const float* xp = xb + r;
#pragma unroll 2
            for (int j = 0; j < 8; ++j) {
                int c = g * 32 + j * 4;
                f32x4 v;
                v[0] = xp[(size_t)(c0 + c + 0) * HW_];
                v[1] = xp[(size_t)(c0 + c + 1) * HW_];
                v[2] = xp[(size_t)(c0 + c + 2) * HW_];
                v[3] = xp[(size_t)(c0 + c + 3) * HW_];
                *(f32x4*)&qs[r * QS + c] = v;
            }
        }
        __syncthreads();
#pragma unroll
        for (int pp = 0; pp < 2; ++pp) {
            const int row = (t + 256 * pp) >> 4;
            const float4* mp = (const float4*)(mempool + (size_t)cnd[pp] * C_ + c0);
            const f32x4* qrow = (const f32x4*)&qs[row * QS];
            float a = racc[pp];
#pragma unroll 8
            for (int u = 0; u < 64; ++u) {
                f32x4 q4 = qrow[u];
                float4 m4 = mp[u];
                a = fmaf(q4[0], m4.x, a);
                a = fmaf(q4[1], m4.y, a);
                a = fmaf(q4[2], m4.z, a);
                a = fmaf(q4[3], m4.w, a);
            }
            racc[pp] = a;
        }
    }
    refv[t] = racc[0];
    refv[t + 256] = racc[1];
    __syncthreads();

    // ---- leader: exact top-8 of 16 + softmax ----
    if (t < TN) {
        const int row = t;
        float rv[16]; int ri[16];
#pragma unroll
        for (int s = 0; s < 16; ++s) { rv[s] = refv[row * 16 + s]; ri[s] = selidx[row * 16 + s]; }
        float wv8[8]; int wi8[8];
#pragma unroll
        for (int sel = 0; sel < 8; ++sel) {
            float vb = NEG_INF; int ib = 0x7fffffff; int sb = 0;
            for (int s = 0; s < 16; ++s) {
                if (rv[s] > vb || (rv[s] == vb && ri[s] < ib)) { vb = rv[s]; ib = ri[s]; sb = s; }
            }
            rv[sb] = NEG_INF;
            wv8[sel] = vb; wi8[sel] = ib;
        }
        const float mx = wv8[0];
        float e[8]; float sum = 0.f;
#pragma unroll
        for (int j = 0; j < 8; ++j) { e[j] = expf(wv8[j] - mx); sum += e[j]; }
        const float inv = 1.f / sum;
#pragma unroll
        for (int j = 0; j < 8; ++j) { w_lds[row * 8 + j] = e[j] * inv; i_lds[row * 8 + j] = wi8[j]; }
    }
    __syncthreads();

    // ---- combine: gathered mempool float4, coalesced-pair stores ----
    const int crow = t & 31;
    const int cw   = t >> 5;      // 0..7, 64 channels each
    float wreg[8]; int ireg[8];
#pragma unroll
    for (int j = 0; j < 8; ++j) { wreg[j] = w_lds[crow * 8 + j]; ireg[j] = i_lds[crow * 8 + j]; }
    float* outb = out + (size_t)b * C_ * HW_ + hw0 + crow;
#pragma unroll 2
    for (int cg = 0; cg < 16; ++cg) {
        const int c = cw * 64 + cg * 4;
        float o0 = 0.f, o1 = 0.f, o2 = 0.f, o3 = 0.f;
#pragma unroll
        for (int j = 0; j < 8; ++j) {
            const float4 mp4 = *(const float4*)&mempool[(size_t)ireg[j] * C_ + c];
            o0 = fmaf(wreg[j], mp4.x, o0);
            o1 = fmaf(wreg[j], mp4.y, o1);
            o2 = fmaf(wreg[j], mp4.z, o2);
            o3 = fmaf(wreg[j], mp4.w, o3);
        }
        outb[(size_t)(c + 0) * HW_] = o0;
        outb[(size_t)(c + 1) * HW_] = o1;
        outb[(size_t)(c + 2) * HW_] = o2;
        outb[(size_t)(c + 3) * HW_] = o3;
    }
}

extern "C" void kernel_launch(void* const* d_in, const int* in_sizes, int n_in,
                              void* d_out, int out_size, void* d_ws, size_t ws_size,
                              hipStream_t stream) {
    const float* x       = (const float*)d_in[0];
    const float* mempool = (const float*)d_in[1];
    unsigned short* membR = (unsigned short*)d_ws;   // 2 MiB bf16 repack
    float* o = (float*)d_out;
    convk<<<dim3(512), dim3(256), 0, stream>>>(mempool, membR);
    memk<<<dim3(1024), dim3(256), 0, stream>>>(x, mempool, membR, o);
}